// Round 16
// baseline (41.356 us; speedup 1.0000x reference)
//
#include <hip/hip_runtime.h>

#define HW 2112L            // 64*33
typedef float f32x4 __attribute__((ext_vector_type(4)));
typedef short s16x8 __attribute__((ext_vector_type(8)));

// ws layout: W B-frag planes (4 x 1MB), then ws2 intermediate at 8MB.
#define WT_PLANE 1048576L
#define OFF_WHR 0L
#define OFF_WLR (WT_PLANE)
#define OFF_WHI (2*WT_PLANE)
#define OFF_WLI (3*WT_PLANE)
#define OFF_WS2 8388608L    // float2[128 bl][32 o][2 r][16 i][16 j] = 16.8 MB

__device__ __forceinline__ ushort f2bf(float f) {
    unsigned u = __float_as_uint(f);
    u += 0x7FFF + ((u >> 16) & 1);          // RNE to bf16
    return (ushort)(u >> 16);
}
__device__ __forceinline__ void split_bf(float v, ushort& hi, ushort& lo) {
    hi = f2bf(v);
    float hf = __uint_as_float(((unsigned)hi) << 16);
    lo = f2bf(v - hf);
}

// =============== K1: W -> B-frag planes (128 blocks, ~2.5us) ===============
__global__ __launch_bounds__(256) void w_prep(
    const float* __restrict__ w1_re, const float* __restrict__ w1_im,
    const float* __restrict__ w2_re, const float* __restrict__ w2_im,
    char* __restrict__ ws)
{
    const int tid = threadIdx.x, bid = blockIdx.x;
    const int r = bid >> 6, i = (bid >> 2) & 15, nt = (bid >> 1) & 1, kh = bid & 1;
    const float* wre = r ? w2_re : w1_re;
    const float* wim = r ? w2_im : w1_im;
    const int col = tid >> 4, j = tid & 15, o = nt * 16 + col;
    const int modeLin = (r * 16 + i) * 16 + j;
    s16x8* phr = (s16x8*)(ws + OFF_WHR);
    s16x8* plr = (s16x8*)(ws + OFF_WLR);
    s16x8* phi = (s16x8*)(ws + OFF_WHI);
    s16x8* pli = (s16x8*)(ws + OFF_WLI);
    #pragma unroll
    for (int kk = 0; kk < 2; ++kk) {
        const int kg = kh * 2 + kk;
        s16x8 hr, lr, hi2, li2;
        #pragma unroll
        for (int e = 0; e < 8; ++e) {
            int c = kg * 8 + e;
            long src = ((long)(c * 32 + o) * 16 + i) * 16 + j;
            ushort a, b;
            split_bf(wre[src], a, b); hr[e] = (short)a; lr[e] = (short)b;
            split_bf(wim[src], a, b); hi2[e] = (short)a; li2[e] = (short)b;
        }
        long off = (long)(modeLin * 2 + nt) * 64 + kg * 16 + col;
        phr[off] = hr; plr[off] = lr; phi[off] = hi2; pli[off] = li2;
    }
}

// =============== K2: compute -> compact ws2 (1024 blocks, 5 blocks/CU) ===============
// A-frag LDS layout (ushort): AF[j]*320 + pl*160 + bl*40 + c  (pl: 0=hi_re, 1=hi_im)
// 16B-aligned b128 reads; one barrier pair; A hi-only + B hi/lo (absmax 2.44e-4, R11).
__global__ __launch_bounds__(256, 5) void k_compute(
    const float* __restrict__ x_re, const float* __restrict__ x_im,
    char* __restrict__ ws)
{
    const int tid = threadIdx.x, bid = blockIdx.x;
    const int r = bid >> 9, i = (bid >> 5) & 15, bt = bid & 31;
    const int h = r ? 48 + i : i;
    const int bl0 = bt * 4;
    const int modeBase = (r * 16 + i) * 16;

    __shared__ __align__(16) ushort AF[16 * 320];     // 10.2 KB
    __shared__ __align__(16) float2 stg[128][17];     // 17.4 KB

    const int wave = tid >> 6, lane = tid & 63;
    const int m = lane & 3, ks = lane >> 4, colo = lane & 15;

    const s16x8* Bwhr = (const s16x8*)(ws + OFF_WHR);
    const s16x8* Bwlr = (const s16x8*)(ws + OFF_WLR);
    const s16x8* Bwhi = (const s16x8*)(ws + OFF_WHI);
    const s16x8* Bwli = (const s16x8*)(ws + OFF_WLI);

    // ---- prefetch B-frags for jj=0 (independent of LDS stage) ----
    const int j0 = wave * 4;
    s16x8 cBhr[2], cBlr[2], cBhi[2], cBli[2];
    {
        long b0 = ((long)(modeBase + j0) * 2 + 0) * 64 + lane;
        long b1 = ((long)(modeBase + j0) * 2 + 1) * 64 + lane;
        cBhr[0] = Bwhr[b0]; cBlr[0] = Bwlr[b0]; cBhi[0] = Bwhi[b0]; cBli[0] = Bwli[b0];
        cBhr[1] = Bwhr[b1]; cBlr[1] = Bwlr[b1]; cBhi[1] = Bwhi[b1]; cBli[1] = Bwli[b1];
    }

    // ---- direct stage: x -> A-frag layout, bf16-hi split at stage time ----
    #pragma unroll
    for (int p = 0; p < 2; ++p) {
        int j4 = tid & 3, c = (tid >> 2) & 31, bl = (tid >> 7) + p * 2;
        long base = ((long)((bl0 + bl) * 32 + c)) * HW + h * 33 + j4 * 4;
        float re0 = x_re[base + 0], re1 = x_re[base + 1], re2 = x_re[base + 2], re3 = x_re[base + 3];
        float im0 = x_im[base + 0], im1 = x_im[base + 1], im2 = x_im[base + 2], im3 = x_im[base + 3];
        int a0 = (j4 * 4) * 320 + bl * 40 + c;
        AF[a0 + 0 * 320]       = f2bf(re0); AF[a0 + 0 * 320 + 160] = f2bf(im0);
        AF[a0 + 1 * 320]       = f2bf(re1); AF[a0 + 1 * 320 + 160] = f2bf(im1);
        AF[a0 + 2 * 320]       = f2bf(re2); AF[a0 + 2 * 320 + 160] = f2bf(im2);
        AF[a0 + 3 * 320]       = f2bf(re3); AF[a0 + 3 * 320 + 160] = f2bf(im3);
    }
    __syncthreads();

    #pragma unroll
    for (int jj = 0; jj < 4; ++jj) {
        const int j = j0 + jj;

        s16x8 nBhr[2], nBlr[2], nBhi[2], nBli[2];
        if (jj < 3) {
            long b0 = ((long)(modeBase + j + 1) * 2 + 0) * 64 + lane;
            long b1 = ((long)(modeBase + j + 1) * 2 + 1) * 64 + lane;
            nBhr[0] = Bwhr[b0]; nBlr[0] = Bwlr[b0]; nBhi[0] = Bwhi[b0]; nBli[0] = Bwli[b0];
            nBhr[1] = Bwhr[b1]; nBlr[1] = Bwlr[b1]; nBhi[1] = Bwhi[b1]; nBli[1] = Bwli[b1];
        }

        s16x8 Ahr = *(const s16x8*)&AF[j * 320 +       m * 40 + ks * 8];
        s16x8 Ahi = *(const s16x8*)&AF[j * 320 + 160 + m * 40 + ks * 8];

        #pragma unroll
        for (int nt = 0; nt < 2; ++nt) {
            f32x4 accP = (f32x4)0.0f, accN = (f32x4)0.0f, accI = (f32x4)0.0f;
            accP = __builtin_amdgcn_mfma_f32_16x16x32_bf16(Ahr, cBhr[nt], accP, 0, 0, 0);
            accP = __builtin_amdgcn_mfma_f32_16x16x32_bf16(Ahr, cBlr[nt], accP, 0, 0, 0);
            accN = __builtin_amdgcn_mfma_f32_16x16x32_bf16(Ahi, cBhi[nt], accN, 0, 0, 0);
            accN = __builtin_amdgcn_mfma_f32_16x16x32_bf16(Ahi, cBli[nt], accN, 0, 0, 0);
            accI = __builtin_amdgcn_mfma_f32_16x16x32_bf16(Ahr, cBhi[nt], accI, 0, 0, 0);
            accI = __builtin_amdgcn_mfma_f32_16x16x32_bf16(Ahr, cBli[nt], accI, 0, 0, 0);
            accI = __builtin_amdgcn_mfma_f32_16x16x32_bf16(Ahi, cBhr[nt], accI, 0, 0, 0);
            accI = __builtin_amdgcn_mfma_f32_16x16x32_bf16(Ahi, cBlr[nt], accI, 0, 0, 0);

            if (ks == 0) {
                #pragma unroll
                for (int q = 0; q < 4; ++q)
                    stg[q * 32 + nt * 16 + colo][j] =
                        make_float2(accP[q] - accN[q], accI[q]);
            }
        }

        if (jj < 3) {
            #pragma unroll
            for (int nt = 0; nt < 2; ++nt) {
                cBhr[nt] = nBhr[nt]; cBlr[nt] = nBlr[nt];
                cBhi[nt] = nBhi[nt]; cBli[nt] = nBli[nt];
            }
        }
    }
    __syncthreads();

    // ---- linear writeout: ws2[bl][o][r][i][j], 128B full-line runs ----
    float2* W2 = (float2*)(ws + OFF_WS2);
    const long base = (long)bl0 * 32 * 512 + r * 256 + i * 16;
    #pragma unroll
    for (int p = 0; p < 8; ++p) {
        int idx = p * 256 + tid;            // [0,2048)
        int j = idx & 15, o = (idx >> 4) & 31, blq = idx >> 9;
        W2[base + (long)blq * 16384 + o * 512 + j] = stg[blq * 32 + o][j];
    }
}

// =============== K3: placer — stream entire output (512 blocks, ~10.5us) ===============
__global__ __launch_bounds__(256) void k_place(
    float* __restrict__ out, const char* __restrict__ ws)
{
    const int tid = threadIdx.x, bid = blockIdx.x;
    const int bl = bid >> 2, oq = bid & 3;
    const float2* W2 = (const float2*)(ws + OFF_WS2);
    float4* out4 = (float4*)out;
    const long outbase4 = ((long)bl * 32 + oq * 8) * 1056;   // float4 units
    const long wbase    = ((long)bl * 32 + oq * 8) * 512;    // float2 units

    #pragma unroll 1
    for (int p = 0; p < 33; ++p) {
        int idx = p * 256 + tid;            // [0, 8448) float4 across 8 planes
        int ol = idx / 1056;
        int f  = idx - ol * 1056;
        int g0 = f * 2, g1 = g0 + 1;        // float2 slots in plane
        int h0 = g0 / 33, w0 = g0 - h0 * 33;
        int h1 = g1 / 33, w1 = g1 - h1 * 33;
        float4 v = make_float4(0.f, 0.f, 0.f, 0.f);
        if (w0 < 16 && (h0 < 16 || h0 >= 48)) {
            float2 t = W2[wbase + (long)ol * 512 + (h0 < 16 ? h0 * 16 : 256 + (h0 - 48) * 16) + w0];
            v.x = t.x; v.y = t.y;
        }
        if (w1 < 16 && (h1 < 16 || h1 >= 48)) {
            float2 t = W2[wbase + (long)ol * 512 + (h1 < 16 ? h1 * 16 : 256 + (h1 - 48) * 16) + w1];
            v.z = t.x; v.w = t.y;
        }
        out4[outbase4 + (long)ol * 1056 + f] = v;
    }
}

extern "C" void kernel_launch(void* const* d_in, const int* in_sizes, int n_in,
                              void* d_out, int out_size, void* d_ws, size_t ws_size,
                              hipStream_t stream) {
    const float* x_re  = (const float*)d_in[0];
    const float* x_im  = (const float*)d_in[1];
    const float* w1_re = (const float*)d_in[2];
    const float* w1_im = (const float*)d_in[3];
    const float* w2_re = (const float*)d_in[4];
    const float* w2_im = (const float*)d_in[5];
    float* out = (float*)d_out;
    char* ws = (char*)d_ws;

    w_prep<<<dim3(128), dim3(256), 0, stream>>>(w1_re, w1_im, w2_re, w2_im, ws);
    k_compute<<<dim3(1024), dim3(256), 0, stream>>>(x_re, x_im, ws);
    k_place<<<dim3(512), dim3(256), 0, stream>>>(out, ws);
}

// Round 17
// 38.985 us; speedup vs baseline: 1.0608x; 1.0608x over previous
//
#include <hip/hip_runtime.h>

#define HW 2112L            // 64*33
typedef float f32x4 __attribute__((ext_vector_type(4)));
typedef short s16x8 __attribute__((ext_vector_type(8)));

// ws: W B-fragment planes. 512 modes * 2 ntiles * 64 lanes * 8 bf16 * 2B = 1 MB/plane.
#define WT_PLANE 1048576L
#define OFF_WHR 0L
#define OFF_WLR (WT_PLANE)
#define OFF_WHI (2*WT_PLANE)
#define OFF_WLI (3*WT_PLANE)

__device__ __forceinline__ ushort f2bf(float f) {
    unsigned u = __float_as_uint(f);
    u += 0x7FFF + ((u >> 16) & 1);          // RNE to bf16
    return (ushort)(u >> 16);
}
__device__ __forceinline__ void split_bf(float v, ushort& hi, ushort& lo) {
    hi = f2bf(v);
    float hf = __uint_as_float(((unsigned)hi) << 16);
    lo = f2bf(v - hf);
}

// =============== K1: wprep role (64 blocks) + middle-band fill (1984 blocks) ===============
// (verbatim from R10, the 34.0 champion)
__global__ __launch_bounds__(256) void k1_prep_fill(
    const float* __restrict__ w1_re, const float* __restrict__ w1_im,
    const float* __restrict__ w2_re, const float* __restrict__ w2_im,
    float* __restrict__ out, char* __restrict__ ws)
{
    const int tid = threadIdx.x, bid = blockIdx.x;

    if (bid >= 64) {
        const int fid = bid - 64;                 // [0,1984)
        int gtid = fid * 256 + tid, n = 1984 * 256;
        float4* out4 = (float4*)out;
        const float4 z = make_float4(0.f, 0.f, 0.f, 0.f);
        for (int idx = gtid; idx < 4096 * 528; idx += n) {
            int plane = idx / 528;
            int k = idx - plane * 528;
            out4[(long)plane * 1056 + 264 + k] = z;
        }
        return;
    }

    const int r = bid >> 5, i = (bid >> 1) & 15, nt = bid & 1;
    const float* wre = r ? w2_re : w1_re;
    const float* wim = r ? w2_im : w1_im;
    const int col = tid >> 4, j = tid & 15, o = nt * 16 + col;
    const int modeLin = (r * 16 + i) * 16 + j;
    s16x8* phr = (s16x8*)(ws + OFF_WHR);
    s16x8* plr = (s16x8*)(ws + OFF_WLR);
    s16x8* phi = (s16x8*)(ws + OFF_WHI);
    s16x8* pli = (s16x8*)(ws + OFF_WLI);
    #pragma unroll
    for (int kg = 0; kg < 4; ++kg) {
        s16x8 hr, lr, hi2, li2;
        #pragma unroll
        for (int e = 0; e < 8; ++e) {
            int c = kg * 8 + e;
            long src = ((long)(c * 32 + o) * 16 + i) * 16 + j;
            ushort a, b;
            split_bf(wre[src], a, b); hr[e] = (short)a; lr[e] = (short)b;
            split_bf(wim[src], a, b); hi2[e] = (short)a; li2[e] = (short)b;
        }
        long off = (long)(modeLin * 2 + nt) * 64 + kg * 16 + col;
        phr[off] = hr; plr[off] = lr; phi[off] = hi2; pli[off] = li2;
    }
}

// =============== K2: compute, 2048 blocks = (r,i,bt,j-half), ~13 KB LDS ===============
// Same algorithm as R10's k2 (A-hi bf16, B hi/lo, jj-pipelined B-frags, direct out
// writes with fused tail zeros) but half the j-range per block: halves the per-block
// critical path, doubles grid granularity, 5 blocks/CU.
__global__ __launch_bounds__(256, 5) void k2_compute(
    const float* __restrict__ x_re, const float* __restrict__ x_im,
    float* __restrict__ out, const char* __restrict__ ws)
{
    const int tid = threadIdx.x, bid = blockIdx.x;
    const int r = bid >> 10, i = (bid >> 6) & 15, bt = (bid >> 1) & 31, jh = bid & 1;
    const int h = r ? 48 + i : i;
    const int bl0 = bt * 4;
    const int modeBase = (r * 16 + i) * 16 + jh * 8;

    __shared__ __align__(16) ushort xfr[8][4][32];    // [jl][bl][c] bf16-hi re, 2KB
    __shared__ __align__(16) ushort xfi[8][4][32];    // 2KB
    __shared__ __align__(16) float2 stg[128][9];      // [bl*32+o][jl pad9] 9.2KB

    const int wave = tid >> 6, lane = tid & 63;
    const int m = lane & 3, ks = lane >> 4, colo = lane & 15;

    const s16x8* Bwhr = (const s16x8*)(ws + OFF_WHR);
    const s16x8* Bwlr = (const s16x8*)(ws + OFF_WLR);
    const s16x8* Bwhi = (const s16x8*)(ws + OFF_WHI);
    const s16x8* Bwli = (const s16x8*)(ws + OFF_WLI);

    // ---- prefetch B-frags for jj=0 (independent of LDS stage) ----
    s16x8 cBhr[2], cBlr[2], cBhi[2], cBli[2];
    {
        long b0 = ((long)(modeBase + wave * 2) * 2 + 0) * 64 + lane;
        long b1 = ((long)(modeBase + wave * 2) * 2 + 1) * 64 + lane;
        cBhr[0] = Bwhr[b0]; cBlr[0] = Bwlr[b0]; cBhi[0] = Bwhi[b0]; cBli[0] = Bwli[b0];
        cBhr[1] = Bwhr[b1]; cBlr[1] = Bwlr[b1]; cBhi[1] = Bwhi[b1]; cBli[1] = Bwli[b1];
    }

    // ---- stage: one float4-pair per thread, split to bf16-hi at stage time ----
    {
        int jq = tid & 1, c = (tid >> 1) & 31, bl = tid >> 6;
        long base = ((long)((bl0 + bl) * 32 + c)) * HW + h * 33 + jh * 8 + jq * 4;
        f32x4 vr = *(const f32x4*)&x_re[base];
        f32x4 vi = *(const f32x4*)&x_im[base];
        #pragma unroll
        for (int q = 0; q < 4; ++q) {
            xfr[jq * 4 + q][bl][c] = f2bf(vr[q]);
            xfi[jq * 4 + q][bl][c] = f2bf(vi[q]);
        }
    }
    __syncthreads();

    // ---- compute: 2 jl per wave, 1-deep B pipeline ----
    #pragma unroll
    for (int jj = 0; jj < 2; ++jj) {
        const int jl = wave * 2 + jj;

        s16x8 nBhr[2], nBlr[2], nBhi[2], nBli[2];
        if (jj == 0) {
            long b0 = ((long)(modeBase + jl + 1) * 2 + 0) * 64 + lane;
            long b1 = ((long)(modeBase + jl + 1) * 2 + 1) * 64 + lane;
            nBhr[0] = Bwhr[b0]; nBlr[0] = Bwlr[b0]; nBhi[0] = Bwhi[b0]; nBli[0] = Bwli[b0];
            nBhr[1] = Bwhr[b1]; nBlr[1] = Bwlr[b1]; nBhi[1] = Bwhi[b1]; nBli[1] = Bwli[b1];
        }

        s16x8 Ahr = *(const s16x8*)&xfr[jl][m][ks * 8];
        s16x8 Ahi = *(const s16x8*)&xfi[jl][m][ks * 8];

        #pragma unroll
        for (int nt = 0; nt < 2; ++nt) {
            f32x4 accP = (f32x4)0.0f, accN = (f32x4)0.0f, accI = (f32x4)0.0f;
            accP = __builtin_amdgcn_mfma_f32_16x16x32_bf16(Ahr, cBhr[nt], accP, 0, 0, 0);
            accP = __builtin_amdgcn_mfma_f32_16x16x32_bf16(Ahr, cBlr[nt], accP, 0, 0, 0);
            accN = __builtin_amdgcn_mfma_f32_16x16x32_bf16(Ahi, cBhi[nt], accN, 0, 0, 0);
            accN = __builtin_amdgcn_mfma_f32_16x16x32_bf16(Ahi, cBli[nt], accN, 0, 0, 0);
            accI = __builtin_amdgcn_mfma_f32_16x16x32_bf16(Ahr, cBhi[nt], accI, 0, 0, 0);
            accI = __builtin_amdgcn_mfma_f32_16x16x32_bf16(Ahr, cBli[nt], accI, 0, 0, 0);
            accI = __builtin_amdgcn_mfma_f32_16x16x32_bf16(Ahi, cBhr[nt], accI, 0, 0, 0);
            accI = __builtin_amdgcn_mfma_f32_16x16x32_bf16(Ahi, cBlr[nt], accI, 0, 0, 0);

            if (ks == 0) {                        // D rows repeat every 4 bl
                #pragma unroll
                for (int q = 0; q < 4; ++q)
                    stg[q * 32 + nt * 16 + colo][jl] =
                        make_float2(accP[q] - accN[q], accI[q]);
            }
        }

        if (jj == 0) {
            #pragma unroll
            for (int nt = 0; nt < 2; ++nt) {
                cBhr[nt] = nBhr[nt]; cBlr[nt] = nBlr[nt];
                cBhi[nt] = nBhi[nt]; cBli[nt] = nBli[nt];
            }
        }
    }
    __syncthreads();

    // ---- writeout: jh0 -> w[0,8); jh1 -> w[8,33) with fused tail zeros ----
    float2* out2 = (float2*)out;
    if (jh == 0) {
        #pragma unroll
        for (int p = 0; p < 4; ++p) {
            int idx = p * 256 + tid;              // [0,1024): row*8 + w
            int row = idx >> 3, w = idx & 7;
            long dst = ((long)(bl0 * 32 + row) * 64 + h) * 33 + w;
            out2[dst] = stg[row][w];
        }
    } else {
        #pragma unroll 2
        for (int t = 0; t < 13; ++t) {
            int idx = t * 256 + tid;              // [0,3328); valid < 3200
            if (idx < 128 * 25) {
                int row = idx / 25;
                int wl = idx - row * 25;          // local w, global = 8 + wl
                float2 v = (wl < 8) ? stg[row][wl] : make_float2(0.f, 0.f);
                long dst = ((long)(bl0 * 32 + row) * 64 + h) * 33 + 8 + wl;
                out2[dst] = v;
            }
        }
    }
}

extern "C" void kernel_launch(void* const* d_in, const int* in_sizes, int n_in,
                              void* d_out, int out_size, void* d_ws, size_t ws_size,
                              hipStream_t stream) {
    const float* x_re  = (const float*)d_in[0];
    const float* x_im  = (const float*)d_in[1];
    const float* w1_re = (const float*)d_in[2];
    const float* w1_im = (const float*)d_in[3];
    const float* w2_re = (const float*)d_in[4];
    const float* w2_im = (const float*)d_in[5];
    float* out = (float*)d_out;
    char* ws = (char*)d_ws;

    k1_prep_fill<<<dim3(2048), dim3(256), 0, stream>>>(
        w1_re, w1_im, w2_re, w2_im, out, ws);
    k2_compute<<<dim3(2048), dim3(256), 0, stream>>>(x_re, x_im, out, ws);
}